// Round 6
// baseline (47.139 us; speedup 1.0000x reference)
//
#include <hip/hip_runtime.h>
#include <stdint.h>

// SkipGram negative-sampling loss on MI355X.
// V=100000, D=128, B=65536, K=20. Output: scalar mean loss (float32).
//
// Structure: pre-pass converts context_emb to fp8 e4m3 (12.8 MB table, HW
// cvt); gather pass reads 128 B fp8 rows, 8 lanes/element (8 elem/wave).
// Round 6: NBLK 2048->1024 so each wave runs exactly TWO grid-stride
// iterations (R5's 1-iter config was pure launch->drain: occ 26%, miss
// path 2.1 TB/s). 16 waves/CU steady state restores the ~110 G-lines/s
// delivered-line ceiling.

#define VOCAB 100000
#define DIM   128
#define BATCH 65536
#define KNEG  20

constexpr int BLOCK = 256;           // 4 waves per block
constexpr int WPB   = BLOCK / 64;
constexpr int NBLK  = 1024;          // 4096 waves -> 2 element-groups per wave
constexpr int GRP   = 8;             // lanes per element
constexpr int EPW   = 64 / GRP;      // 8 elements per wave
constexpr int FPL   = DIM / GRP;     // 16 floats per lane (center rows)

typedef float floatx2 __attribute__((ext_vector_type(2)));

// ---------- f32 -> fp8 e4m3 (RNE, HW cvt) streaming conversion ----------
__global__ __launch_bounds__(256)
void conv_fp8(const float4* __restrict__ src, uint4* __restrict__ dst, int n16)
{
    const int tid    = blockIdx.x * blockDim.x + threadIdx.x;
    const int stride = gridDim.x * blockDim.x;
    for (int i = tid; i < n16; i += stride) {
        float4 a0 = src[4 * i + 0], a1 = src[4 * i + 1];
        float4 a2 = src[4 * i + 2], a3 = src[4 * i + 3];
        uint32_t w0 = 0, w1 = 0, w2 = 0, w3 = 0;
        w0 = __builtin_amdgcn_cvt_pk_fp8_f32(a0.x, a0.y, w0, 0);
        w0 = __builtin_amdgcn_cvt_pk_fp8_f32(a0.z, a0.w, w0, 1);
        w1 = __builtin_amdgcn_cvt_pk_fp8_f32(a1.x, a1.y, w1, 0);
        w1 = __builtin_amdgcn_cvt_pk_fp8_f32(a1.z, a1.w, w1, 1);
        w2 = __builtin_amdgcn_cvt_pk_fp8_f32(a2.x, a2.y, w2, 0);
        w2 = __builtin_amdgcn_cvt_pk_fp8_f32(a2.z, a2.w, w2, 1);
        w3 = __builtin_amdgcn_cvt_pk_fp8_f32(a3.x, a3.y, w3, 0);
        w3 = __builtin_amdgcn_cvt_pk_fp8_f32(a3.z, a3.w, w3, 1);
        uint4 o; o.x = w0; o.y = w1; o.z = w2; o.w = w3;
        dst[i] = o;
    }
}

// ---------- main gather/dot kernel (fp8 context table, GRP=8) ----------
__global__ __launch_bounds__(BLOCK)
void sg_main_fp8(const int* __restrict__ center,
                 const int* __restrict__ context,
                 const int* __restrict__ negatives,
                 const float* __restrict__ center_emb,
                 const uint32_t* __restrict__ ctx_tbl,   // V * 32 uint32 (4 fp8 each)
                 float* __restrict__ block_sums)
{
    const int lane = threadIdx.x & 63;
    const int lig  = lane & (GRP - 1);   // lane in 8-lane group
    const int grp  = lane >> 3;          // element slot in wave (0..7)
    const int wib  = threadIdx.x >> 6;
    const int gwave = blockIdx.x * WPB + wib;
    const int nwv   = NBLK * WPB;        // 4096 waves -> 2 iterations each

    float acc = 0.0f;

    for (int eb = gwave; eb < BATCH / EPW; eb += nwv) {
        const int b  = eb * EPW + grp;
        const int ci = center[b];
        const int pi = context[b];

        int idx[KNEG];
        const int4* np4 = (const int4*)(negatives + (size_t)b * KNEG);
        #pragma unroll
        for (int q = 0; q < KNEG / 4; ++q) {
            int4 v = np4[q];
            idx[q * 4 + 0] = v.x; idx[q * 4 + 1] = v.y;
            idx[q * 4 + 2] = v.z; idx[q * 4 + 3] = v.w;
        }

        // center row: lane covers dims [lig*16, lig*16+16)
        const float4* vcp = (const float4*)(center_emb + (size_t)ci * DIM + lig * FPL);
        const float4 vc0 = vcp[0], vc1 = vcp[1], vc2 = vcp[2], vc3 = vcp[3];

        // fp8 rows: one uint4 (16 fp8) per lane per row (row = 128 B)
        auto rowp = [&](int r) -> const uint4* {
            return (const uint4*)(ctx_tbl + (size_t)r * (DIM / 4)) + lig;
        };
        auto fdot = [&](uint4 r) -> float {
            floatx2 p;
            float d = 0.0f;
            p = __builtin_amdgcn_cvt_pk_f32_fp8((int)r.x, 0); d += vc0.x * p.x + vc0.y * p.y;
            p = __builtin_amdgcn_cvt_pk_f32_fp8((int)r.x, 1); d += vc0.z * p.x + vc0.w * p.y;
            p = __builtin_amdgcn_cvt_pk_f32_fp8((int)r.y, 0); d += vc1.x * p.x + vc1.y * p.y;
            p = __builtin_amdgcn_cvt_pk_f32_fp8((int)r.y, 1); d += vc1.z * p.x + vc1.w * p.y;
            p = __builtin_amdgcn_cvt_pk_f32_fp8((int)r.z, 0); d += vc2.x * p.x + vc2.y * p.y;
            p = __builtin_amdgcn_cvt_pk_f32_fp8((int)r.z, 1); d += vc2.z * p.x + vc2.w * p.y;
            p = __builtin_amdgcn_cvt_pk_f32_fp8((int)r.w, 0); d += vc3.x * p.x + vc3.y * p.y;
            p = __builtin_amdgcn_cvt_pk_f32_fp8((int)r.w, 1); d += vc3.z * p.x + vc3.w * p.y;
            return d;
        };

        float s[KNEG + 1];
        s[0] = fdot(*rowp(pi));
        #pragma unroll
        for (int k = 0; k < KNEG; ++k)
            s[k + 1] = fdot(*rowp(idx[k]));

        // 3-round butterfly within each 8-lane group
        #pragma unroll
        for (int off = 4; off >= 1; off >>= 1) {
            #pragma unroll
            for (int j = 0; j <= KNEG; ++j)
                s[j] += __shfl_xor(s[j], off, 64);
        }

        // all 8 lanes hold s[0..20]; lane lig evaluates terms lig, lig+8, lig+16
        float x = s[0];                       // lane 0: +pos; lanes 1..7: -neg
        #pragma unroll
        for (int j = 1; j < GRP; ++j)
            x = (lig == j) ? -s[j] : x;
        {
            float sig = 1.0f / (1.0f + __expf(-x));
            acc += -__logf(sig + 1e-8f);
        }
        float y = -s[GRP];
        #pragma unroll
        for (int j = GRP + 1; j < 2 * GRP; ++j)
            y = (lig == j - GRP) ? -s[j] : y;
        {
            float sig = 1.0f / (1.0f + __expf(-y));
            acc += -__logf(sig + 1e-8f);
        }
        float z = -s[2 * GRP];
        #pragma unroll
        for (int j = 2 * GRP + 1; j <= KNEG; ++j)
            z = (lig == j - 2 * GRP) ? -s[j] : z;
        if (lig < KNEG + 1 - 2 * GRP) {
            float sig = 1.0f / (1.0f + __expf(-z));
            acc += -__logf(sig + 1e-8f);
        }
    }

    #pragma unroll
    for (int off = 32; off >= 1; off >>= 1)
        acc += __shfl_xor(acc, off, 64);

    __shared__ float ws[WPB];
    if (lane == 0) ws[wib] = acc;
    __syncthreads();
    if (threadIdx.x == 0) {
        float t = 0.0f;
        #pragma unroll
        for (int i = 0; i < WPB; ++i) t += ws[i];
        block_sums[blockIdx.x] = t;
    }
}

// ---------- fallback f32 kernel (used only if ws too small) ----------
__global__ __launch_bounds__(BLOCK)
void sg_main_f32(const int* __restrict__ center,
                 const int* __restrict__ context,
                 const int* __restrict__ negatives,
                 const float* __restrict__ center_emb,
                 const float* __restrict__ context_emb,
                 float* __restrict__ block_sums)
{
    const int lane = threadIdx.x & 63;
    const int lig  = lane & 15;
    const int grp  = lane >> 4;
    const int wib  = threadIdx.x >> 6;
    const int gwave = blockIdx.x * WPB + wib;
    const int nwv   = NBLK * WPB;

    float acc = 0.0f;

    for (int eb = gwave; eb < BATCH / 4; eb += nwv) {
        const int b  = eb * 4 + grp;
        const int ci = center[b];
        const int pi = context[b];

        int idx[KNEG];
        const int4* np4 = (const int4*)(negatives + (size_t)b * KNEG);
        #pragma unroll
        for (int q = 0; q < KNEG / 4; ++q) {
            int4 v = np4[q];
            idx[q * 4 + 0] = v.x; idx[q * 4 + 1] = v.y;
            idx[q * 4 + 2] = v.z; idx[q * 4 + 3] = v.w;
        }

        const float4* vcp = (const float4*)(center_emb + (size_t)ci * DIM + lig * 8);
        const float4 vc0 = vcp[0], vc1 = vcp[1];

        float s[KNEG + 1];
        {
            const float4* rp = (const float4*)(context_emb + (size_t)pi * DIM + lig * 8);
            const float4 r0 = rp[0], r1 = rp[1];
            s[0] = vc0.x * r0.x + vc0.y * r0.y + vc0.z * r0.z + vc0.w * r0.w
                 + vc1.x * r1.x + vc1.y * r1.y + vc1.z * r1.z + vc1.w * r1.w;
        }
        #pragma unroll
        for (int k = 0; k < KNEG; ++k) {
            const float4* rp = (const float4*)(context_emb + (size_t)idx[k] * DIM + lig * 8);
            const float4 r0 = rp[0], r1 = rp[1];
            s[k + 1] = vc0.x * r0.x + vc0.y * r0.y + vc0.z * r0.z + vc0.w * r0.w
                     + vc1.x * r1.x + vc1.y * r1.y + vc1.z * r1.z + vc1.w * r1.w;
        }

        #pragma unroll
        for (int off = 8; off >= 1; off >>= 1) {
            #pragma unroll
            for (int j = 0; j <= KNEG; ++j)
                s[j] += __shfl_xor(s[j], off, 64);
        }

        float x = s[0];
        #pragma unroll
        for (int j = 1; j < 16; ++j)
            x = (lig == j) ? -s[j] : x;
        {
            float sig = 1.0f / (1.0f + __expf(-x));
            acc += -__logf(sig + 1e-8f);
        }
        float y = -s[16];
        #pragma unroll
        for (int j = 17; j <= KNEG; ++j)
            y = (lig == j - 16) ? -s[j] : y;
        if (lig < KNEG + 1 - 16) {
            float sig = 1.0f / (1.0f + __expf(-y));
            acc += -__logf(sig + 1e-8f);
        }
    }

    #pragma unroll
    for (int off = 32; off >= 1; off >>= 1)
        acc += __shfl_xor(acc, off, 64);

    __shared__ float ws[WPB];
    if (lane == 0) ws[wib] = acc;
    __syncthreads();
    if (threadIdx.x == 0) {
        float t = 0.0f;
        #pragma unroll
        for (int i = 0; i < WPB; ++i) t += ws[i];
        block_sums[blockIdx.x] = t;
    }
}

__global__ __launch_bounds__(BLOCK)
void sg_finish(const float* __restrict__ block_sums, float* __restrict__ out, int n)
{
    const int lane = threadIdx.x & 63;
    const int wib  = threadIdx.x >> 6;

    float t = 0.0f;
    for (int i = threadIdx.x; i < n; i += BLOCK) t += block_sums[i];

    #pragma unroll
    for (int off = 32; off >= 1; off >>= 1)
        t += __shfl_xor(t, off, 64);

    __shared__ float ws[WPB];
    if (lane == 0) ws[wib] = t;
    __syncthreads();
    if (threadIdx.x == 0) {
        float s = 0.0f;
        #pragma unroll
        for (int i = 0; i < WPB; ++i) s += ws[i];
        out[0] = s * (1.0f / (float)BATCH);
    }
}

extern "C" void kernel_launch(void* const* d_in, const int* in_sizes, int n_in,
                              void* d_out, int out_size, void* d_ws, size_t ws_size,
                              hipStream_t stream)
{
    const int*   center      = (const int*)  d_in[0];
    const int*   context     = (const int*)  d_in[1];
    const int*   negatives   = (const int*)  d_in[2];
    const float* center_emb  = (const float*)d_in[3];
    const float* context_emb = (const float*)d_in[4];
    float*       out         = (float*)d_out;

    const size_t tbl_bytes = (size_t)VOCAB * DIM;   // 12.8 MB fp8 table

    if (ws_size >= tbl_bytes + NBLK * sizeof(float)) {
        uint32_t* tbl        = (uint32_t*)d_ws;
        float*    block_sums = (float*)((char*)d_ws + tbl_bytes);

        conv_fp8<<<2048, 256, 0, stream>>>((const float4*)context_emb,
                                           (uint4*)tbl, VOCAB * DIM / 16);
        sg_main_fp8<<<NBLK, BLOCK, 0, stream>>>(center, context, negatives,
                                                center_emb, tbl, block_sums);
        sg_finish<<<1, BLOCK, 0, stream>>>(block_sums, out, NBLK);
    } else {
        float* block_sums = (float*)d_ws;
        sg_main_f32<<<NBLK, BLOCK, 0, stream>>>(center, context, negatives,
                                                center_emb, context_emb, block_sums);
        sg_finish<<<1, BLOCK, 0, stream>>>(block_sums, out, NBLK);
    }
}